// Round 5
// baseline (2308.952 us; speedup 1.0000x reference)
//
#include <hip/hip_runtime.h>

#define NN 100000
#define DD 128
#define NE 3200000
#define NBUK 196           // buckets per support, 512 rows each
#define NSH 8              // shards per bucket (XCD affinity)
#define NBS (2 * NBUK * NSH)   // 3136 sharded counters

// ---------------- GEMM: g[m,n] = sum_k h[m,k] * W[n,k] + b[n] ----------------
// STORE_BF16: 0 -> f32 g, 1 -> bf16 g (RNE)
template <int STORE_BF16>
__global__ __launch_bounds__(256) void gemm_xwt(const float* __restrict__ h,
                                                const float* __restrict__ W,
                                                const float* __restrict__ b,
                                                void* __restrict__ gout) {
    __shared__ float Wl[128 * 128];
    const int t = threadIdx.x;
    for (int i = t * 4; i < 128 * 128; i += 256 * 4) {
        const int n = i >> 7;
        const int k = i & 127;
        const float4 w = *(const float4*)&W[i];
        *(float4*)&Wl[(n << 7) + ((((k >> 2) ^ (n & 7)) << 2))] = w;
    }
    __syncthreads();

    const int tc = t & 15;
    const int tr = t >> 4;
    const int r0 = blockIdx.x * 64 + tr * 4;

    int rr[4];
#pragma unroll
    for (int j = 0; j < 4; ++j) rr[j] = min(r0 + j, NN - 1);

    float acc[4][8];
#pragma unroll
    for (int i = 0; i < 8; ++i) {
        const float bv = b[tc + 16 * i];
#pragma unroll
        for (int j = 0; j < 4; ++j) acc[j][i] = bv;
    }

#pragma unroll 2
    for (int k0 = 0; k0 < 128; k0 += 4) {
        float4 hv[4];
#pragma unroll
        for (int j = 0; j < 4; ++j)
            hv[j] = *(const float4*)&h[(size_t)rr[j] * DD + k0];
#pragma unroll
        for (int i = 0; i < 8; ++i) {
            const int n = tc + 16 * i;
            const float4 wv =
                *(const float4*)&Wl[(n << 7) + ((((k0 >> 2) ^ (n & 7)) << 2))];
#pragma unroll
            for (int j = 0; j < 4; ++j) {
                acc[j][i] += hv[j].x * wv.x;
                acc[j][i] += hv[j].y * wv.y;
                acc[j][i] += hv[j].z * wv.z;
                acc[j][i] += hv[j].w * wv.w;
            }
        }
    }

#pragma unroll
    for (int j = 0; j < 4; ++j) {
        const int r = r0 + j;
        if (r < NN) {
            if (STORE_BF16) {
                unsigned short* gp = (unsigned short*)gout + (size_t)r * DD;
#pragma unroll
                for (int i = 0; i < 8; ++i) {
                    const unsigned int u = __float_as_uint(acc[j][i]);
                    const unsigned short bf =
                        (unsigned short)((u + 0x7FFFu + ((u >> 16) & 1u)) >> 16);
                    gp[tc + 16 * i] = bf;
                }
            } else {
                float* gp = (float*)gout + (size_t)r * DD;
#pragma unroll
                for (int i = 0; i < 8; ++i) gp[tc + 16 * i] = acc[j][i];
            }
        }
    }
}

// ---------------- bucketed CSR build ----------------
// shard by (e>>8)&7: with grid 4096 (mult of 8) & 256-thr blocks, all edges of
// a (bucket,shard) cell are appended by blocks with the same bid&7 (same XCD
// under round-robin dispatch) -> append writes L2-merge, no amplification.
__global__ __launch_bounds__(256) void bcount(const int* __restrict__ rows,
                                              int* __restrict__ bcnt8) {
    for (int e = blockIdx.x * 256 + threadIdx.x; e < 2 * NE;
         e += gridDim.x * 256) {
        const int s = (e >= NE);
        const int r = rows[e];
        atomicAdd(&bcnt8[((s * NBUK + (r >> 9)) << 3) + ((e >> 8) & 7)], 1);
    }
}

// single block, 1024 threads, 4 entries each (3136 padded to 4096)
__global__ __launch_bounds__(1024) void bscan(const int* __restrict__ bcnt8,
                                              int* __restrict__ bbase8,
                                              int* __restrict__ bcur8,
                                              int* __restrict__ rp2) {
    __shared__ int tmp[1024];
    const int tid = threadIdx.x;
    int v[4];
    int s = 0;
#pragma unroll
    for (int q = 0; q < 4; ++q) {
        const int i = tid * 4 + q;
        v[q] = (i < NBS) ? bcnt8[i] : 0;
        s += v[q];
    }
    tmp[tid] = s;
    __syncthreads();
    for (int off = 1; off < 1024; off <<= 1) {
        const int t = (tid >= off) ? tmp[tid - off] : 0;
        __syncthreads();
        tmp[tid] += t;
        __syncthreads();
    }
    int excl = tmp[tid] - s;
#pragma unroll
    for (int q = 0; q < 4; ++q) {
        const int i = tid * 4 + q;
        if (i < NBS) {
            bbase8[i] = excl;
            bcur8[i] = excl;
        }
        excl += v[q];
    }
    if (tid == 1023) bbase8[NBS] = tmp[1023];
    if (tid == 0) {
        rp2[NN] = NE;
        rp2[(NN + 1) + NN] = NE;
    }
}

// scatter into sharded bucket regions; payload packs (rowlocal<<17)|col
__global__ __launch_bounds__(256) void bscatter(const float* __restrict__ vals,
                                                const int* __restrict__ rows,
                                                const int* __restrict__ cols,
                                                int* __restrict__ bcur8,
                                                int2* __restrict__ aux) {
    for (int e = blockIdx.x * 256 + threadIdx.x; e < 2 * NE;
         e += gridDim.x * 256) {
        const int s = (e >= NE);
        const int r = rows[e];
        const int idx = ((s * NBUK + (r >> 9)) << 3) + ((e >> 8) & 7);
        const int pos = atomicAdd(&bcur8[idx], 1);
        aux[pos] = make_int2(((r & 511) << 17) | cols[e], __float_as_int(vals[e]));
    }
}

// per-bucket sort: one 512-thread block per bucket; builds final pairs + rp
__global__ __launch_bounds__(512) void bsort(const int2* __restrict__ aux,
                                             const int* __restrict__ bbase8,
                                             int2* __restrict__ pairs,
                                             int* __restrict__ rp2) {
    __shared__ int hist[512], scn[512], cur[512];
    const int b = blockIdx.x;
    const int s = b / NBUK;
    const int brow0 = (b - s * NBUK) << 9;
    const int base = bbase8[b << 3];
    const int nE = bbase8[(b + 1) << 3] - base;
    const int tid = threadIdx.x;

    hist[tid] = 0;
    __syncthreads();
    for (int i = tid; i < nE; i += 512)
        atomicAdd(&hist[aux[base + i].x >> 17], 1);
    __syncthreads();
    scn[tid] = hist[tid];
    __syncthreads();
    for (int off = 1; off < 512; off <<= 1) {
        const int t = (tid >= off) ? scn[tid - off] : 0;
        __syncthreads();
        scn[tid] += t;
        __syncthreads();
    }
    const int excl = scn[tid] - hist[tid];
    cur[tid] = excl;
    const int row = brow0 + tid;
    if (row < NN) rp2[s * (NN + 1) + row] = (base - s * NE) + excl;
    __syncthreads();
    for (int i = tid; i < nE; i += 512) {
        const int2 p = aux[base + i];
        const int rl = p.x >> 17;
        const int pos = base + atomicAdd(&cur[rl], 1);
        pairs[pos] = make_int2(p.x & 0x1FFFF, p.y);
    }
}

// ---------------- row-parallel CSR SpMM (bf16 gather source) ----------------
// MODE: 0 = y[r]=tanh(acc) (f32), 1 = y[r]=acc, 3 = y[r]=tanh(y[r]+acc+x[r])
template <int MODE>
__global__ __launch_bounds__(256) void spmm_csr(const int* __restrict__ rp,
                                                const int2* __restrict__ pairs,
                                                const char* __restrict__ gb,
                                                const float* __restrict__ x,
                                                float* __restrict__ y) {
    const int w = (blockIdx.x << 2) + (threadIdx.x >> 6);
    if (w >= NN) return;
    const int lane = threadIdx.x & 63;
    const int beg = rp[w];
    const int end = rp[w + 1];
    float2 acc = {0.f, 0.f};
    int j = beg;
    for (; j + 4 <= end; j += 4) {
        int2 p[4];
#pragma unroll
        for (int q = 0; q < 4; ++q) p[q] = pairs[j + q];
        unsigned int u[4];
#pragma unroll
        for (int q = 0; q < 4; ++q)
            u[q] = *(const unsigned int*)(gb + ((size_t)p[q].x << 8) + (lane << 2));
#pragma unroll
        for (int q = 0; q < 4; ++q) {
            const float v = __int_as_float(p[q].y);
            acc.x += v * __uint_as_float(u[q] << 16);
            acc.y += v * __uint_as_float(u[q] & 0xFFFF0000u);
        }
    }
    for (; j < end; ++j) {
        const int2 p = pairs[j];
        const float v = __int_as_float(p.y);
        const unsigned int u =
            *(const unsigned int*)(gb + ((size_t)p.x << 8) + (lane << 2));
        acc.x += v * __uint_as_float(u << 16);
        acc.y += v * __uint_as_float(u & 0xFFFF0000u);
    }
    float* yp = &y[(size_t)w * DD + (lane << 1)];
    if (MODE == 0) {
        float2 r;
        r.x = tanhf(acc.x);
        r.y = tanhf(acc.y);
        *(float2*)yp = r;
    } else if (MODE == 1) {
        *(float2*)yp = acc;
    } else {
        const float2 xv = *(const float2*)&x[(size_t)w * DD + (lane << 1)];
        const float2 o = *(const float2*)yp;
        float2 r;
        r.x = tanhf(o.x + acc.x + xv.x);
        r.y = tanhf(o.y + acc.y + xv.y);
        *(float2*)yp = r;
    }
}

// ---------------- atomic fallback (tier 2, f32 g) ----------------
__global__ __launch_bounds__(256) void spmm_at(const float* __restrict__ vals,
                                               const int* __restrict__ rows,
                                               const int* __restrict__ cols,
                                               const float* __restrict__ g,
                                               float* __restrict__ y) {
    const int gid = blockIdx.x * 256 + threadIdx.x;
    const int f4 = (gid & 31) << 2;
    const int estride = (gridDim.x * 256) >> 5;
    for (int e = gid >> 5; e < NE; e += estride) {
        const float v = vals[e];
        const int r = rows[e];
        const int c = cols[e];
        const float4 gv = *(const float4*)&g[(size_t)c * DD + f4];
        float* yp = &y[(size_t)r * DD + f4];
        atomicAdd(yp + 0, v * gv.x);
        atomicAdd(yp + 1, v * gv.y);
        atomicAdd(yp + 2, v * gv.z);
        atomicAdd(yp + 3, v * gv.w);
    }
}

__global__ __launch_bounds__(256) void tanh_ip(float* __restrict__ y) {
    const size_t n4 = (size_t)NN * DD / 4;
    for (size_t i = (size_t)blockIdx.x * 256 + threadIdx.x; i < n4;
         i += (size_t)gridDim.x * 256) {
        float4 v = ((float4*)y)[i];
        v.x = tanhf(v.x);
        v.y = tanhf(v.y);
        v.z = tanhf(v.z);
        v.w = tanhf(v.w);
        ((float4*)y)[i] = v;
    }
}

__global__ __launch_bounds__(256) void final_act(float* __restrict__ out,
                                                 const float* __restrict__ x) {
    const size_t n4 = (size_t)NN * DD / 4;
    for (size_t i = (size_t)blockIdx.x * 256 + threadIdx.x; i < n4;
         i += (size_t)gridDim.x * 256) {
        const float4 a = ((const float4*)x)[i];
        float4 v = ((float4*)out)[i];
        v.x = tanhf(v.x + a.x);
        v.y = tanhf(v.y + a.y);
        v.z = tanhf(v.z + a.z);
        v.w = tanhf(v.w + a.w);
        ((float4*)out)[i] = v;
    }
}

extern "C" void kernel_launch(void* const* d_in, const int* in_sizes, int n_in,
                              void* d_out, int out_size, void* d_ws, size_t ws_size,
                              hipStream_t stream) {
    const float* x    = (const float*)d_in[0];
    const float* Ws   = (const float*)d_in[1];
    const float* bs   = (const float*)d_in[2];
    const float* vals = (const float*)d_in[3];
    const int*   rows = (const int*)d_in[4];
    const int*   cols = (const int*)d_in[5];
    float* out = (float*)d_out;

    const size_t GB16  = (size_t)NN * DD * 2;                       // 25.6 MB bf16 g
    const size_t FB    = (size_t)NN * DD * sizeof(float);           // 51.2 MB
    const size_t PAIRB = (size_t)2 * NE * 8;                        // 51.2 MB
    const size_t RP2B  = ((size_t)2 * (NN + 1) * 4 + 127) & ~(size_t)127;
    const size_t BCB   = ((size_t)(NBS + 8) * 4 + 127) & ~(size_t)127;

    const size_t need_csr = GB16 + FB /*y|aux*/ + PAIRB + RP2B + 3 * BCB; // ~129 MB

    char* p = (char*)d_ws;

    if (ws_size >= need_csr) {
        char*  g     = p;          p += GB16;   // bf16 g
        char*  yaux  = p;          p += FB;     // f32 y  (overlays int2 aux)
        int2*  pairs = (int2*)p;   p += PAIRB;
        int*   rp2   = (int*)p;    p += RP2B;
        int*   bcnt8 = (int*)p;    p += BCB;
        int*   bbase8= (int*)p;    p += BCB;
        int*   bcur8 = (int*)p;    p += BCB;

        float* y   = (float*)yaux;
        int2*  aux = (int2*)yaux;

        // ---- build bucketed CSR (both supports) ----
        hipMemsetAsync(bcnt8, 0, (size_t)NBS * 4, stream);
        bcount<<<4096, 256, 0, stream>>>(rows, bcnt8);
        bscan<<<1, 1024, 0, stream>>>(bcnt8, bbase8, bcur8, rp2);
        bscatter<<<4096, 256, 0, stream>>>(vals, rows, cols, bcur8, aux);
        bsort<<<2 * NBUK, 512, 0, stream>>>(aux, bbase8, pairs, rp2);
        // aux region is now free; reused as y below

        const int sgrid = (NN + 3) / 4;
        for (int s = 0; s < 2; ++s) {
            const float* W0 = Ws + (size_t)(s * 2 + 0) * DD * DD;
            const float* W1 = Ws + (size_t)(s * 2 + 1) * DD * DD;
            const float* b0 = bs + (size_t)(s * 2 + 0) * DD;
            const float* b1 = bs + (size_t)(s * 2 + 1) * DD;
            const int*  rp = rp2 + (size_t)s * (NN + 1);
            const int2* pr = pairs + (size_t)s * NE;

            gemm_xwt<1><<<(NN + 63) / 64, 256, 0, stream>>>(x, W0, b0, g);
            spmm_csr<0><<<sgrid, 256, 0, stream>>>(rp, pr, g, nullptr, y);
            gemm_xwt<1><<<(NN + 63) / 64, 256, 0, stream>>>(y, W1, b1, g);
            if (s == 0)
                spmm_csr<1><<<sgrid, 256, 0, stream>>>(rp, pr, g, nullptr, out);
            else  // fused: out = tanh(out + A g + x)
                spmm_csr<3><<<sgrid, 256, 0, stream>>>(rp, pr, g, x, out);
        }
        return;
    }

    // ---- fallback: atomic SpMM (ws >= 2*FB) ----
    float* g = (float*)p;
    float* y = g + (size_t)NN * DD;
    hipMemsetAsync(out, 0, FB, stream);
    for (int s = 0; s < 2; ++s) {
        const float* W0 = Ws + (size_t)(s * 2 + 0) * DD * DD;
        const float* W1 = Ws + (size_t)(s * 2 + 1) * DD * DD;
        const float* b0 = bs + (size_t)(s * 2 + 0) * DD;
        const float* b1 = bs + (size_t)(s * 2 + 1) * DD;
        const float* vs = vals + (size_t)s * NE;
        const int*   rs = rows + (size_t)s * NE;
        const int*   cs = cols + (size_t)s * NE;

        gemm_xwt<0><<<(NN + 63) / 64, 256, 0, stream>>>(x, W0, b0, g);
        hipMemsetAsync(y, 0, FB, stream);
        spmm_at<<<8192, 256, 0, stream>>>(vs, rs, cs, g, y);
        tanh_ip<<<4096, 256, 0, stream>>>(y);
        gemm_xwt<0><<<(NN + 63) / 64, 256, 0, stream>>>(y, W1, b1, g);
        spmm_at<<<8192, 256, 0, stream>>>(vs, rs, cs, g, out);
    }
    final_act<<<4096, 256, 0, stream>>>(out, x);
}